// Round 4
// baseline (119.041 us; speedup 1.0000x reference)
//
#include <hip/hip_runtime.h>

// Problem constants (fixed by setup_inputs)
constexpr int NB  = 4;     // batch
constexpr int NPT = 2048;  // points (N)
constexpr int KNN = 32;    // neighbors (K)
constexpr int CIN = 6;     // in_channels
constexpr int CF  = 64;    // feat channels
constexpr int CO  = 64;    // out channels
constexpr float EPS = 1e-5f;

typedef short bf16x8 __attribute__((ext_vector_type(8)));   // 8 bf16 in 4 VGPRs
typedef float f32x4  __attribute__((ext_vector_type(4)));

// ---------------- workspace layout (bytes) ----------------
constexpr size_t WS_WA  = 0;       // WAf bf16[6*4*2*64*8] (sa-folded, row-permuted)
constexpr size_t WS_WL  = 49152;   // WLf bf16[4*2*64*8]  (sl-folded)
constexpr size_t WS_WR  = 57344;   // WRf bf16[4*2*64*8]  (sr-folded)
constexpr size_t WS_BA  = 65536;   // baP f32[6*64]
constexpr size_t WS_BNF = 67072;   // bnf f32[3*64]  (s1, b1, blr)

__device__ __host__ inline unsigned short bf16_rne(float f) {
  unsigned u = __builtin_bit_cast(unsigned, f);
  u += 0x7fffu + ((u >> 16) & 1u);
  return (unsigned short)(u >> 16);
}

__global__ void setup_kernel(const float *Wattn, const float *Wlin, const float *Wres,
                             const float *ga, const float *ba, const float *ma, const float *va,
                             const float *g1, const float *b1, const float *m1, const float *v1,
                             const float *gl, const float *bl, const float *ml, const float *vl,
                             const float *gr, const float *br, const float *mr, const float *vr,
                             unsigned short *WAf, unsigned short *WLf, unsigned short *WRf,
                             float *baP, float *bnf) {
  const int t = blockIdx.x * blockDim.x + threadIdx.x;
  const int stride = gridDim.x * blockDim.x;
  for (int e = t; e < 6 * 4 * 2 * 64 * 8; e += stride) {
    const int j = e & 7, l = (e >> 3) & 63, ks = (e >> 9) & 1, ot = (e >> 10) & 3, i = e >> 12;
    const int m = l & 15, cg = l >> 4;
    const int cc = ks * 32 + cg * 8 + j;
    const int row = (ot * 16 + m) * CIN + i;
    const float sa = ga[row] * rsqrtf(va[row] + EPS);
    WAf[e] = bf16_rne(Wattn[row * CF + cc] * sa);
  }
  for (int e = t; e < 4 * 2 * 64 * 8; e += stride) {
    const int j = e & 7, l = (e >> 3) & 63, ks = (e >> 9) & 1, ot = e >> 10;
    const int m = l & 15;
    const int cc = ks * 32 + (l >> 4) * 8 + j;
    const int row = ot * 16 + m;
    const float sl = gl[row] * rsqrtf(vl[row] + EPS);
    const float sr = gr[row] * rsqrtf(vr[row] + EPS);
    WLf[e] = bf16_rne(Wlin[row * CF + cc] * sl);
    WRf[e] = bf16_rne(Wres[row * CF + cc] * sr);
  }
  for (int e = t; e < 384; e += stride) {
    const int i = e >> 6, o = e & 63;
    const int j0 = o * CIN + i;
    const float sa = ga[j0] * rsqrtf(va[j0] + EPS);
    baP[e] = ba[j0] - ma[j0] * sa;
  }
  for (int e = t; e < 64; e += stride) {
    const float s1v = g1[e] * rsqrtf(v1[e] + EPS);
    bnf[e]      = s1v;
    bnf[64 + e] = b1[e] - m1[e] * s1v;
    const float slv = gl[e] * rsqrtf(vl[e] + EPS);
    const float srv = gr[e] * rsqrtf(vr[e] + EPS);
    bnf[128 + e] = (bl[e] - ml[e] * slv) + (br[e] - mr[e] * srv);
  }
}

struct Params {
  const float *x, *y, *points, *feat;
  const float *Wq, *Wpos1, *Wpos2;
  const float *gq, *bq, *mq, *vq;
  const float *gp, *bp, *mp, *vp;
  const unsigned short *WAf, *WLf, *WRf;
  const float *baP, *bnf;
  float *out;
};

// One wave per 2 consecutive points; no block barriers. Per point, ONE 4KB
// bf16 B-buffer recycled y -> P -> h (fragments hoisted to regs before each
// overwrite; in-wave DS ordering makes this safe).
__global__ __launch_bounds__(256, 4) void fused_pt_attn(Params p) {
  const int tid  = threadIdx.x;
  const int lane = tid & 63;
  const int wid  = tid >> 6;
  // XCD-aware swizzle over 1024 blocks (8 XCDs x 128 contiguous).
  const int bid  = ((blockIdx.x & 7) << 7) | (blockIdx.x >> 3);
  const int pb   = (bid * 4 + wid) * 2;     // even point index
  const int b    = pb >> 11;
  const int n0   = pb & (NPT - 1);          // n1 = n0 + 1 (same b)

  __shared__ unsigned short s_BB[4][2][2048];  // [wave][pt] 4KB bf16 frag buffer
  __shared__ float s_d[4][2][192];             // d = pos1 - x
  __shared__ float s_f[4][2][32];              // feat
  unsigned short *BB0 = s_BB[wid][0], *BB1 = s_BB[wid][1];
  float *dW0 = s_d[wid][0], *dW1 = s_d[wid][1];
  float *fW0 = s_f[wid][0], *fW1 = s_f[wid][1];

  // ---- global stage (both points; consecutive n -> paired loads) ----
  float2 ft2 = make_float2(0.f, 0.f), pt2 = make_float2(0.f, 0.f);
  if (lane < 32) ft2 = *(const float2 *)(p.feat + ((size_t)b * 32 + lane) * NPT + n0);
  if (lane < 3)  pt2 = *(const float2 *)(p.points + ((size_t)b * 3 + lane) * NPT + n0);
  const int xi = lane >> 3, xk = (lane & 7) * 4;
  float4 x40 = make_float4(0.f, 0.f, 0.f, 0.f), x41 = x40;
  if (lane < 48) {
    const float *xb = p.x + (((size_t)b * CIN + xi) * NPT + n0) * KNN + xk;
    x40 = *(const float4 *)(xb);
    x41 = *(const float4 *)(xb + KNN);
  }
  const float *w2p = p.Wpos2 + lane * 6;
  const float2 w2a = *(const float2 *)(w2p);
  const float2 w2b = *(const float2 *)(w2p + 2);
  const float2 w2c = *(const float2 *)(w2p + 4);
  const float w2[6] = {w2a.x, w2a.y, w2b.x, w2b.y, w2c.x, w2c.y};

  if (lane < 32) { fW0[lane] = ft2.x; fW1[lane] = ft2.y; }

  // ---- pos1 for both points (Wpos1/BN loads shared) ----
  const float pA0 = __shfl(pt2.x, 0), pA1 = __shfl(pt2.x, 1), pA2 = __shfl(pt2.x, 2);
  const float pB0 = __shfl(pt2.y, 0), pB1 = __shfl(pt2.y, 1), pB2 = __shfl(pt2.y, 2);
  float pos10[6], pos11[6];
#pragma unroll
  for (int i = 0; i < 6; ++i) {
    const float w0 = p.Wpos1[i * 3 + 0], w1 = p.Wpos1[i * 3 + 1], wv = p.Wpos1[i * 3 + 2];
    const float s  = p.gp[i] * rsqrtf(p.vp[i] + EPS);
    const float bb = p.bp[i] - p.mp[i] * s;
    float a0 = fmaf(w0, pA0, fmaf(w1, pA1, wv * pA2));
    a0 = fmaf(a0, s, bb);
    pos10[i] = a0 > 0.f ? a0 : 0.2f * a0;
    float a1 = fmaf(w0, pB0, fmaf(w1, pB1, wv * pB2));
    a1 = fmaf(a1, s, bb);
    pos11[i] = a1 > 0.f ? a1 : 0.2f * a1;
  }

  // ---- d = pos1 - x (lanes 0..47, 4 elems per point) ----
  if (lane < 48) {
    float pi0 = pos10[0], pi1 = pos11[0];
    pi0 = (xi == 1) ? pos10[1] : pi0;  pi1 = (xi == 1) ? pos11[1] : pi1;
    pi0 = (xi == 2) ? pos10[2] : pi0;  pi1 = (xi == 2) ? pos11[2] : pi1;
    pi0 = (xi == 3) ? pos10[3] : pi0;  pi1 = (xi == 3) ? pos11[3] : pi1;
    pi0 = (xi == 4) ? pos10[4] : pi0;  pi1 = (xi == 4) ? pos11[4] : pi1;
    pi0 = (xi == 5) ? pos10[5] : pi0;  pi1 = (xi == 5) ? pos11[5] : pi1;
    *(float4 *)(dW0 + xi * 32 + xk) = make_float4(pi0 - x40.x, pi0 - x40.y, pi0 - x40.z, pi0 - x40.w);
    *(float4 *)(dW1 + xi * 32 + xk) = make_float4(pi1 - x41.x, pi1 - x41.y, pi1 - x41.z, pi1 - x41.w);
  }

  // ---- x_q for both points (one pass over Wq row) ----
  float xq0, xq1;
  {
    float a0 = 0.f, a1 = 0.f;
    const float *wq = p.Wq + lane * 32;
#pragma unroll
    for (int q = 0; q < 8; ++q) {
      const float4 w4 = *(const float4 *)(wq + q * 4);
      const float4 f0 = *(const float4 *)(fW0 + q * 4);
      const float4 f1 = *(const float4 *)(fW1 + q * 4);
      a0 = fmaf(w4.x, f0.x, fmaf(w4.y, f0.y, fmaf(w4.z, f0.z, fmaf(w4.w, f0.w, a0))));
      a1 = fmaf(w4.x, f1.x, fmaf(w4.y, f1.y, fmaf(w4.z, f1.z, fmaf(w4.w, f1.w, a1))));
    }
    const float s  = p.gq[lane] * rsqrtf(p.vq[lane] + EPS);
    const float bb = p.bq[lane] - p.mq[lane] * s;
    const float v0 = fmaf(a0, s, bb), v1 = fmaf(a1, s, bb);
    xq0 = v0 > 0.f ? v0 : 0.2f * v0;
    xq1 = v1 > 0.f ? v1 : 0.2f * v1;
  }

  // ---- pre = sum_i w2[i]*d[i][k] for both points ----
  float pre0[32], pre1[32];
#pragma unroll
  for (int k = 0; k < 32; ++k) { pre0[k] = 0.f; pre1[k] = 0.f; }
#pragma unroll
  for (int i = 0; i < 6; ++i) {
    const float wv = w2[i];
#pragma unroll
    for (int q = 0; q < 8; ++q) {
      const float4 d0 = *(const float4 *)(dW0 + i * 32 + q * 4);
      const float4 d1 = *(const float4 *)(dW1 + i * 32 + q * 4);
      pre0[q * 4 + 0] = fmaf(wv, d0.x, pre0[q * 4 + 0]);
      pre0[q * 4 + 1] = fmaf(wv, d0.y, pre0[q * 4 + 1]);
      pre0[q * 4 + 2] = fmaf(wv, d0.z, pre0[q * 4 + 2]);
      pre0[q * 4 + 3] = fmaf(wv, d0.w, pre0[q * 4 + 3]);
      pre1[q * 4 + 0] = fmaf(wv, d1.x, pre1[q * 4 + 0]);
      pre1[q * 4 + 1] = fmaf(wv, d1.y, pre1[q * 4 + 1]);
      pre1[q * 4 + 2] = fmaf(wv, d1.z, pre1[q * 4 + 2]);
      pre1[q * 4 + 3] = fmaf(wv, d1.w, pre1[q * 4 + 3]);
    }
  }

  // ---- stream y (both points), stash as bf16 frags, finalize pre ----
  const float *yrow0 = p.y + (((size_t)b * CF + lane) * NPT + n0) * KNN;
#pragma unroll
  for (int q = 0; q < 8; ++q) {
    const float4 y0 = *(const float4 *)(yrow0 + q * 4);
    const float4 y1 = *(const float4 *)(yrow0 + KNN + q * 4);
    const float yv0[4] = {y0.x, y0.y, y0.z, y0.w};
    const float yv1[4] = {y1.x, y1.y, y1.z, y1.w};
#pragma unroll
    for (int j = 0; j < 4; ++j) {
      const int k = q * 4 + j;
      const int idx = k * 64 + (lane ^ ((k & 7) << 3));
      BB0[idx] = bf16_rne(yv0[j]);
      BB1[idx] = bf16_rne(yv1[j]);
      pre0[k] = (xq0 - yv0[j] + pre0[k]) * 0.125f;
      pre1[k] = (xq1 - yv1[j] + pre1[k]) * 0.125f;
    }
  }

  const int og = lane >> 4, kl = lane & 15;

  // ---- hoist y B-fragments to regs (before P overwrites buffers) ----
  bf16x8 By0[2][2], By1[2][2];
#pragma unroll
  for (int ks = 0; ks < 2; ++ks)
#pragma unroll
    for (int nt = 0; nt < 2; ++nt) {
      const int kcol = kl + nt * 16;
      const int off = kcol * 64 + ((ks * 32 + og * 8) ^ ((kl & 7) << 3));
      By0[ks][nt] = *(const bf16x8 *)(BB0 + off);
      By1[ks][nt] = *(const bf16x8 *)(BB1 + off);
    }

  // ---- in-lane softmax, write P over y-buffer ----
  {
    float mx0 = pre0[0], mx1 = pre1[0];
#pragma unroll
    for (int k = 1; k < 32; ++k) { mx0 = fmaxf(mx0, pre0[k]); mx1 = fmaxf(mx1, pre1[k]); }
    float s0 = 0.f, s1 = 0.f;
#pragma unroll
    for (int k = 0; k < 32; ++k) {
      pre0[k] = __expf(pre0[k] - mx0); s0 += pre0[k];
      pre1[k] = __expf(pre1[k] - mx1); s1 += pre1[k];
    }
    const float i0 = 1.f / s0, i1 = 1.f / s1;
#pragma unroll
    for (int k = 0; k < 32; ++k) {
      const int idx = k * 64 + (lane ^ ((k & 7) << 3));
      BB0[idx] = bf16_rne(pre0[k] * i0);
      BB1[idx] = bf16_rne(pre1[k] * i1);
    }
  }

  // ---- P B-fragments ----
  bf16x8 Ba0[2][2], Ba1[2][2];
#pragma unroll
  for (int ks = 0; ks < 2; ++ks)
#pragma unroll
    for (int nt = 0; nt < 2; ++nt) {
      const int kcol = kl + nt * 16;
      const int off = kcol * 64 + ((ks * 32 + og * 8) ^ ((kl & 7) << 3));
      Ba0[ks][nt] = *(const bf16x8 *)(BB0 + off);
      Ba1[ks][nt] = *(const bf16x8 *)(BB1 + off);
    }

  // ---- x-combine scalars, bf16-pair packed (nt0 lo, nt1 hi): 12 regs ----
  unsigned xvp0[6], xvp1[6];
#pragma unroll
  for (int i = 0; i < 6; ++i) {
    const float a0 = pos10[i] - dW0[i * 32 + kl];
    const float c0 = pos10[i] - dW0[i * 32 + kl + 16];
    const float a1 = pos11[i] - dW1[i * 32 + kl];
    const float c1 = pos11[i] - dW1[i * 32 + kl + 16];
    xvp0[i] = (unsigned)bf16_rne(a0) | ((unsigned)bf16_rne(c0) << 16);
    xvp1[i] = (unsigned)bf16_rne(a1) | ((unsigned)bf16_rne(c1) << 16);
  }

  // ---- GEMM1 (A-frags shared by both points) + combine + BN1 + h-write ----
  const bf16x8 *WAv = (const bf16x8 *)p.WAf;
#pragma unroll
  for (int ot = 0; ot < 4; ++ot) {
    f32x4 o00 = {0.f, 0.f, 0.f, 0.f}, o01 = o00, o10 = o00, o11 = o00;  // [pt][nt]
#pragma unroll
    for (int i = 0; i < 6; ++i) {
      const bf16x8 A0 = WAv[((i * 4 + ot) * 2 + 0) * 64 + lane];
      const bf16x8 A1 = WAv[((i * 4 + ot) * 2 + 1) * 64 + lane];
      const f32x4 ba4 = *(const f32x4 *)(p.baP + i * 64 + ot * 16 + og * 4);
      const float xv00 = __builtin_bit_cast(float, xvp0[i] << 16);
      const float xv01 = __builtin_bit_cast(float, xvp0[i] & 0xffff0000u);
      const float xv10 = __builtin_bit_cast(float, xvp1[i] << 16);
      const float xv11 = __builtin_bit_cast(float, xvp1[i] & 0xffff0000u);
      f32x4 g;
      g = (f32x4){0.f, 0.f, 0.f, 0.f};
      g = __builtin_amdgcn_mfma_f32_16x16x32_bf16(A0, Ba0[0][0], g, 0, 0, 0);
      g = __builtin_amdgcn_mfma_f32_16x16x32_bf16(A1, Ba0[1][0], g, 0, 0, 0);
#pragma unroll
      for (int r = 0; r < 4; ++r) o00[r] = fmaf(g[r] + ba4[r], xv00, o00[r]);
      g = (f32x4){0.f, 0.f, 0.f, 0.f};
      g = __builtin_amdgcn_mfma_f32_16x16x32_bf16(A0, Ba0[0][1], g, 0, 0, 0);
      g = __builtin_amdgcn_mfma_f32_16x16x32_bf16(A1, Ba0[1][1], g, 0, 0, 0);
#pragma unroll
      for (int r = 0; r < 4; ++r) o01[r] = fmaf(g[r] + ba4[r], xv01, o01[r]);
      g = (f32x4){0.f, 0.f, 0.f, 0.f};
      g = __builtin_amdgcn_mfma_f32_16x16x32_bf16(A0, Ba1[0][0], g, 0, 0, 0);
      g = __builtin_amdgcn_mfma_f32_16x16x32_bf16(A1, Ba1[1][0], g, 0, 0, 0);
#pragma unroll
      for (int r = 0; r < 4; ++r) o10[r] = fmaf(g[r] + ba4[r], xv10, o10[r]);
      g = (f32x4){0.f, 0.f, 0.f, 0.f};
      g = __builtin_amdgcn_mfma_f32_16x16x32_bf16(A0, Ba1[0][1], g, 0, 0, 0);
      g = __builtin_amdgcn_mfma_f32_16x16x32_bf16(A1, Ba1[1][1], g, 0, 0, 0);
#pragma unroll
      for (int r = 0; r < 4; ++r) o11[r] = fmaf(g[r] + ba4[r], xv11, o11[r]);
    }
    const f32x4 s14 = *(const f32x4 *)(p.bnf + 0 * 64 + ot * 16 + og * 4);
    const f32x4 b14 = *(const f32x4 *)(p.bnf + 1 * 64 + ot * 16 + og * 4);
#pragma unroll
    for (int nt = 0; nt < 2; ++nt) {
      const int kcol = kl + nt * 16;
      const int idx = kcol * 64 + ((ot * 16 + og * 4) ^ ((kl & 7) << 3));
      const f32x4 &q0 = nt ? o01 : o00;
      const f32x4 &q1 = nt ? o11 : o10;
      unsigned h0[4], h1[4];
#pragma unroll
      for (int r = 0; r < 4; ++r) {
        const float t0 = fmaf(s14[r], q0[r], b14[r]);
        const float t1 = fmaf(s14[r], q1[r], b14[r]);
        h0[r] = bf16_rne(t0 > 0.f ? t0 : 0.2f * t0);
        h1[r] = bf16_rne(t1 > 0.f ? t1 : 0.2f * t1);
      }
      *(uint2 *)(BB0 + idx) = make_uint2(h0[0] | (h0[1] << 16), h0[2] | (h0[3] << 16));
      *(uint2 *)(BB1 + idx) = make_uint2(h1[0] | (h1[1] << 16), h1[2] | (h1[3] << 16));
    }
  }

  // ---- h B-fragments ----
  bf16x8 Bh0[2][2], Bh1[2][2];
#pragma unroll
  for (int ks = 0; ks < 2; ++ks)
#pragma unroll
    for (int nt = 0; nt < 2; ++nt) {
      const int kcol = kl + nt * 16;
      const int off = kcol * 64 + ((ks * 32 + og * 8) ^ ((kl & 7) << 3));
      Bh0[ks][nt] = *(const bf16x8 *)(BB0 + off);
      Bh1[ks][nt] = *(const bf16x8 *)(BB1 + off);
    }

  // ---- GEMM2: lrelu( Wlin'@h + Wres'@y + blr ), weights shared ----
  const bf16x8 *WLv = (const bf16x8 *)p.WLf;
  const bf16x8 *WRv = (const bf16x8 *)p.WRf;
#pragma unroll
  for (int ot = 0; ot < 4; ++ot) {
    const bf16x8 L0 = WLv[(ot * 2 + 0) * 64 + lane];
    const bf16x8 L1 = WLv[(ot * 2 + 1) * 64 + lane];
    const bf16x8 R0 = WRv[(ot * 2 + 0) * 64 + lane];
    const bf16x8 R1 = WRv[(ot * 2 + 1) * 64 + lane];
    const f32x4 blr = *(const f32x4 *)(p.bnf + 2 * 64 + ot * 16 + og * 4);
#pragma unroll
    for (int nt = 0; nt < 2; ++nt) {
      f32x4 a0 = {0.f, 0.f, 0.f, 0.f}, a1 = a0;
      a0 = __builtin_amdgcn_mfma_f32_16x16x32_bf16(L0, Bh0[0][nt], a0, 0, 0, 0);
      a0 = __builtin_amdgcn_mfma_f32_16x16x32_bf16(L1, Bh0[1][nt], a0, 0, 0, 0);
      a0 = __builtin_amdgcn_mfma_f32_16x16x32_bf16(R0, By0[0][nt], a0, 0, 0, 0);
      a0 = __builtin_amdgcn_mfma_f32_16x16x32_bf16(R1, By0[1][nt], a0, 0, 0, 0);
      a1 = __builtin_amdgcn_mfma_f32_16x16x32_bf16(L0, Bh1[0][nt], a1, 0, 0, 0);
      a1 = __builtin_amdgcn_mfma_f32_16x16x32_bf16(L1, Bh1[1][nt], a1, 0, 0, 0);
      a1 = __builtin_amdgcn_mfma_f32_16x16x32_bf16(R0, By1[0][nt], a1, 0, 0, 0);
      a1 = __builtin_amdgcn_mfma_f32_16x16x32_bf16(R1, By1[1][nt], a1, 0, 0, 0);
      const int kcol = kl + nt * 16;
      float *ob = p.out + (((size_t)(b * CO + ot * 16 + og * 4)) * NPT + n0) * KNN + kcol;
#pragma unroll
      for (int r = 0; r < 4; ++r) {
        const float v0 = a0[r] + blr[r];
        const float v1 = a1[r] + blr[r];
        ob[(size_t)r * NPT * KNN]       = v0 > 0.f ? v0 : 0.2f * v0;
        ob[(size_t)r * NPT * KNN + KNN] = v1 > 0.f ? v1 : 0.2f * v1;
      }
    }
  }
}

extern "C" void kernel_launch(void *const *d_in, const int *in_sizes, int n_in,
                              void *d_out, int out_size, void *d_ws, size_t ws_size,
                              hipStream_t stream) {
  char *ws = (char *)d_ws;
  unsigned short *WAf = (unsigned short *)(ws + WS_WA);
  unsigned short *WLf = (unsigned short *)(ws + WS_WL);
  unsigned short *WRf = (unsigned short *)(ws + WS_WR);
  float *baP = (float *)(ws + WS_BA);
  float *bnf = (float *)(ws + WS_BNF);

  setup_kernel<<<dim3(96), dim3(256), 0, stream>>>(
      (const float *)d_in[7], (const float *)d_in[8], (const float *)d_in[9],
      (const float *)d_in[18], (const float *)d_in[19], (const float *)d_in[20], (const float *)d_in[21],
      (const float *)d_in[22], (const float *)d_in[23], (const float *)d_in[24], (const float *)d_in[25],
      (const float *)d_in[26], (const float *)d_in[27], (const float *)d_in[28], (const float *)d_in[29],
      (const float *)d_in[30], (const float *)d_in[31], (const float *)d_in[32], (const float *)d_in[33],
      WAf, WLf, WRf, baP, bnf);

  Params p;
  p.x      = (const float *)d_in[0];
  p.y      = (const float *)d_in[1];
  p.points = (const float *)d_in[2];
  p.feat   = (const float *)d_in[3];
  p.Wq     = (const float *)d_in[4];
  p.Wpos1  = (const float *)d_in[5];
  p.Wpos2  = (const float *)d_in[6];
  p.gq = (const float *)d_in[10]; p.bq = (const float *)d_in[11];
  p.mq = (const float *)d_in[12]; p.vq = (const float *)d_in[13];
  p.gp = (const float *)d_in[14]; p.bp = (const float *)d_in[15];
  p.mp = (const float *)d_in[16]; p.vp = (const float *)d_in[17];
  p.WAf = WAf; p.WLf = WLf; p.WRf = WRf;
  p.baP = baP; p.bnf = bnf;
  p.out = (float *)d_out;

  fused_pt_attn<<<dim3(NB * NPT / 8), dim3(256), 0, stream>>>(p);
}